// Round 2
// baseline (8120.721 us; speedup 1.0000x reference)
//
#include <hip/hip_runtime.h>

// LightGCN: 3-layer propagation on a 1.6M-edge graph, D=128, all f32.
// Inputs: uEmbeds f32 [50000,128], iEmbeds f32 [50000,128],
//         edge_src i32 [1.6M], edge_dst i32 [1.6M], edge_val f32 [1.6M]
// Output f32 [100000,128] = embeds + sum of 3 propagation layers (node order).
// d_out doubles as the f32 accumulator. Workspace: bufA, bufB (2 x 51.2 MB).

static constexpr int USERS  = 50000;
static constexpr int NNODES = 100000;
static constexpr int DIM    = 128;
static constexpr int NEDGES = 1600000;
static constexpr int NLAYERS = 3;
static constexpr long NELEM = (long)NNODES * DIM;   // 12.8M floats

// Concat u/i embeds -> acc (= d_out) and cur. float4 x2 per thread.
__global__ void init_k(const float* __restrict__ uE,
                       const float* __restrict__ iE,
                       float* __restrict__ acc, float* __restrict__ cur) {
    long base = ((long)blockIdx.x * blockDim.x + threadIdx.x) * 8;
    if (base >= NELEM) return;
    const long usplit = (long)USERS * DIM;              // 6.4M, divisible by 8
    const float* s = (base < usplit) ? (uE + base) : (iE + (base - usplit));
    float4 f0 = *(const float4*)(s);
    float4 f1 = *(const float4*)(s + 4);
    *(float4*)(acc + base)     = f0;
    *(float4*)(acc + base + 4) = f1;
    *(float4*)(cur + base)     = f0;
    *(float4*)(cur + base + 4) = f1;
}

// COO scatter: 32 lanes per edge, 4 dims per lane (float4 gather + 4 atomics).
__global__ void scatter_k(const int* __restrict__ esrc, const int* __restrict__ edst,
                          const float* __restrict__ eval,
                          const float* __restrict__ cur, float* __restrict__ nxt) {
    long g = (long)blockIdx.x * blockDim.x + threadIdx.x;
    if (g >= (long)NEDGES * 32) return;
    int e  = (int)(g >> 5);
    int d0 = ((int)g & 31) * 4;
    int s  = esrc[e];
    int t  = edst[e];
    float v = eval[e];
    float4 x = *(const float4*)(cur + (long)s * DIM + d0);
    float* o = nxt + (long)t * DIM + d0;
    unsafeAtomicAdd(o + 0, x.x * v);   // HW global_atomic_add_f32 (no CAS loop)
    unsafeAtomicAdd(o + 1, x.y * v);
    unsafeAtomicAdd(o + 2, x.z * v);
    unsafeAtomicAdd(o + 3, x.w * v);
}

// acc += nxt, float4 per thread
__global__ void add_k(float* __restrict__ acc, const float* __restrict__ nxt) {
    long g = ((long)blockIdx.x * blockDim.x + threadIdx.x) * 4;
    if (g >= NELEM) return;
    float4 a = *(const float4*)(acc + g);
    float4 n = *(const float4*)(nxt + g);
    a.x += n.x; a.y += n.y; a.z += n.z; a.w += n.w;
    *(float4*)(acc + g) = a;
}

extern "C" void kernel_launch(void* const* d_in, const int* in_sizes, int n_in,
                              void* d_out, int out_size, void* d_ws, size_t ws_size,
                              hipStream_t stream) {
    const float* uE   = (const float*)d_in[0];
    const float* iE   = (const float*)d_in[1];
    const int*   esrc = (const int*)d_in[2];
    const int*   edst = (const int*)d_in[3];
    const float* eval = (const float*)d_in[4];

    float* acc  = (float*)d_out;         // 51.2 MB, accumulate in place
    float* bufA = (float*)d_ws;          // 51.2 MB
    float* bufB = bufA + NELEM;          // 51.2 MB
    const size_t SZ = (size_t)NELEM * sizeof(float);

    init_k<<<(int)((NELEM / 8 + 255) / 256), 256, 0, stream>>>(uE, iE, acc, bufA);

    float* cur = bufA;
    float* nxt = bufB;
    for (int l = 0; l < NLAYERS; ++l) {
        hipMemsetAsync(nxt, 0, SZ, stream);
        long nthreads = (long)NEDGES * 32;               // 51.2M
        scatter_k<<<(int)((nthreads + 255) / 256), 256, 0, stream>>>(esrc, edst, eval, cur, nxt);
        add_k<<<(int)((NELEM / 4 + 255) / 256), 256, 0, stream>>>(acc, nxt);
        float* t = cur; cur = nxt; nxt = t;
    }
}

// Round 3
// 729.749 us; speedup vs baseline: 11.1281x; 11.1281x over previous
//
#include <hip/hip_runtime.h>

// LightGCN: 3-layer propagation, 1.6M edges, D=128, f32.
// R3: CSR-by-destination built per launch; per-layer gather (1 wave / dest row)
// replaces 614M f32 atomics (R2 bottleneck: 3.2GB atomic write-through per layer).

static constexpr int USERS  = 50000;
static constexpr int NNODES = 100000;
static constexpr int DIM    = 128;
static constexpr int NEDGES = 1600000;
static constexpr int NLAYERS = 3;
static constexpr long NELEM = (long)NNODES * DIM;   // 12.8M floats
static constexpr int SCAN_BLK = 256;
static constexpr int NBLKS = (NNODES + SCAN_BLK - 1) / SCAN_BLK;  // 391

// ---------- shared helpers ----------
__global__ void init_k(const float* __restrict__ uE,
                       const float* __restrict__ iE,
                       float* __restrict__ acc, float* __restrict__ cur) {
    long base = ((long)blockIdx.x * blockDim.x + threadIdx.x) * 8;
    if (base >= NELEM) return;
    const long usplit = (long)USERS * DIM;
    const float* s = (base < usplit) ? (uE + base) : (iE + (base - usplit));
    float4 f0 = *(const float4*)(s);
    float4 f1 = *(const float4*)(s + 4);
    *(float4*)(acc + base)     = f0;
    *(float4*)(acc + base + 4) = f1;
    *(float4*)(cur + base)     = f0;
    *(float4*)(cur + base + 4) = f1;
}

// ---------- CSR build ----------
__global__ void hist_k(const int* __restrict__ edst, int* __restrict__ counts) {
    int e = blockIdx.x * blockDim.x + threadIdx.x;
    if (e >= NEDGES) return;
    atomicAdd(&counts[edst[e]], 1);
}

// per-block inclusive scan -> exclusive out + block sums
__global__ void scan1_k(const int* __restrict__ counts, int* __restrict__ rs,
                        int* __restrict__ blk) {
    __shared__ int s[SCAN_BLK];
    int t = threadIdx.x;
    int i = blockIdx.x * SCAN_BLK + t;
    int v = (i < NNODES) ? counts[i] : 0;
    s[t] = v;
    __syncthreads();
    for (int off = 1; off < SCAN_BLK; off <<= 1) {
        int x = (t >= off) ? s[t - off] : 0;
        __syncthreads();
        s[t] += x;
        __syncthreads();
    }
    if (i < NNODES) rs[i] = s[t] - v;            // exclusive
    if (t == SCAN_BLK - 1) blk[blockIdx.x] = s[t];
}

// scan 391 block sums in one block of 512
__global__ void scan2_k(int* __restrict__ blk) {
    __shared__ int s[512];
    int t = threadIdx.x;
    int v = (t < NBLKS) ? blk[t] : 0;
    s[t] = v;
    __syncthreads();
    for (int off = 1; off < 512; off <<= 1) {
        int x = (t >= off) ? s[t - off] : 0;
        __syncthreads();
        s[t] += x;
        __syncthreads();
    }
    if (t < NBLKS) blk[t] = s[t] - v;            // exclusive block offsets
}

__global__ void scan3_k(int* __restrict__ rs, const int* __restrict__ blk,
                        int* __restrict__ cursor) {
    int i = blockIdx.x * SCAN_BLK + threadIdx.x;
    if (i == 0) rs[NNODES] = NEDGES;
    if (i >= NNODES) return;
    int v = rs[i] + blk[blockIdx.x];
    rs[i] = v;
    cursor[i] = v;
}

__global__ void fill_k(const int* __restrict__ esrc, const int* __restrict__ edst,
                       const float* __restrict__ eval,
                       int* __restrict__ cursor, int2* __restrict__ meta) {
    int e = blockIdx.x * blockDim.x + threadIdx.x;
    if (e >= NEDGES) return;
    int d = edst[e];
    int p = atomicAdd(&cursor[d], 1);
    meta[p] = make_int2(esrc[e], __float_as_int(eval[e]));
}

// ---------- per-layer gather: 1 wave per dest row, float2 per lane ----------
__global__ void gather_k(const int* __restrict__ rs, const int2* __restrict__ meta,
                         const float* __restrict__ cur, float* __restrict__ nxt,
                         float* __restrict__ acc) {
    int row = blockIdx.x * (blockDim.x >> 6) + (threadIdx.x >> 6);
    if (row >= NNODES) return;
    int lane = threadIdx.x & 63;
    int beg = rs[row], end = rs[row + 1];
    float2 sum = make_float2(0.f, 0.f);
    for (int i = beg; i < end; ++i) {
        int2 m = meta[i];                                   // broadcast 8B
        float v = __int_as_float(m.y);
        float2 x = *(const float2*)(cur + (long)m.x * DIM + lane * 2);
        sum.x += x.x * v;
        sum.y += x.y * v;
    }
    long o = (long)row * DIM + lane * 2;
    *(float2*)(nxt + o) = sum;
    float2 a = *(const float2*)(acc + o);
    a.x += sum.x; a.y += sum.y;
    *(float2*)(acc + o) = a;
}

// ---------- fallback (R2 path, needs only 102.4MB ws) ----------
__global__ void scatter_k(const int* __restrict__ esrc, const int* __restrict__ edst,
                          const float* __restrict__ eval,
                          const float* __restrict__ cur, float* __restrict__ nxt) {
    long g = (long)blockIdx.x * blockDim.x + threadIdx.x;
    if (g >= (long)NEDGES * 32) return;
    int e  = (int)(g >> 5);
    int d0 = ((int)g & 31) * 4;
    float v = eval[e];
    float4 x = *(const float4*)(cur + (long)esrc[e] * DIM + d0);
    float* o = nxt + (long)edst[e] * DIM + d0;
    unsafeAtomicAdd(o + 0, x.x * v);
    unsafeAtomicAdd(o + 1, x.y * v);
    unsafeAtomicAdd(o + 2, x.z * v);
    unsafeAtomicAdd(o + 3, x.w * v);
}

__global__ void add_k(float* __restrict__ acc, const float* __restrict__ nxt) {
    long g = ((long)blockIdx.x * blockDim.x + threadIdx.x) * 4;
    if (g >= NELEM) return;
    float4 a = *(const float4*)(acc + g);
    float4 n = *(const float4*)(nxt + g);
    a.x += n.x; a.y += n.y; a.z += n.z; a.w += n.w;
    *(float4*)(acc + g) = a;
}

extern "C" void kernel_launch(void* const* d_in, const int* in_sizes, int n_in,
                              void* d_out, int out_size, void* d_ws, size_t ws_size,
                              hipStream_t stream) {
    const float* uE   = (const float*)d_in[0];
    const float* iE   = (const float*)d_in[1];
    const int*   esrc = (const int*)d_in[2];
    const int*   edst = (const int*)d_in[3];
    const float* eval = (const float*)d_in[4];

    float* acc  = (float*)d_out;
    char*  ws   = (char*)d_ws;
    float* bufA = (float*)ws;                       // 51.2 MB
    float* bufB = bufA + NELEM;                     // 51.2 MB
    const size_t SZ = (size_t)NELEM * sizeof(float);

    // CSR region after the two buffers
    int2* meta   = (int2*)(ws + 2 * SZ);            // 12.8 MB (8B aligned)
    int*  rs     = (int*)(meta + NEDGES);           // NNODES+1
    int*  cursor = rs + NNODES + 1;                 // NNODES (doubles as counts)
    int*  blk    = cursor + NNODES;                 // 512
    size_t need  = (size_t)((char*)(blk + 512) - ws);

    init_k<<<(int)((NELEM / 8 + 255) / 256), 256, 0, stream>>>(uE, iE, acc, bufA);

    if (ws_size >= need) {
        // --- CSR build ---
        hipMemsetAsync(cursor, 0, (size_t)NNODES * sizeof(int), stream);
        hist_k<<<(NEDGES + 255) / 256, 256, 0, stream>>>(edst, cursor);
        scan1_k<<<NBLKS, SCAN_BLK, 0, stream>>>(cursor, rs, blk);
        scan2_k<<<1, 512, 0, stream>>>(blk);
        scan3_k<<<NBLKS, SCAN_BLK, 0, stream>>>(rs, blk, cursor);
        fill_k<<<(NEDGES + 255) / 256, 256, 0, stream>>>(esrc, edst, eval, cursor, meta);

        // --- 3 gather layers, acc update fused ---
        float* cur = bufA;
        float* nxt = bufB;
        for (int l = 0; l < NLAYERS; ++l) {
            gather_k<<<(NNODES * 64 + 255) / 256, 256, 0, stream>>>(rs, meta, cur, nxt, acc);
            float* t = cur; cur = nxt; nxt = t;
        }
    } else {
        // --- fallback: atomic scatter (R2) ---
        float* cur = bufA;
        float* nxt = bufB;
        for (int l = 0; l < NLAYERS; ++l) {
            hipMemsetAsync(nxt, 0, SZ, stream);
            long nthreads = (long)NEDGES * 32;
            scatter_k<<<(int)((nthreads + 255) / 256), 256, 0, stream>>>(esrc, edst, eval, cur, nxt);
            add_k<<<(int)((NELEM / 4 + 255) / 256), 256, 0, stream>>>(acc, nxt);
            float* t = cur; cur = nxt; nxt = t;
        }
    }
}

// Round 4
// 520.041 us; speedup vs baseline: 15.6155x; 1.4033x over previous
//
#include <hip/hip_runtime.h>

// LightGCN: 3-layer propagation, 1.6M edges, D=128.
// R4: bf16 intermediate layer buffers. R3 showed gather FETCH = 408MB = 8 XCDs
// x 51.2MB cur buffer (full XCD-L2 replication of the random-gather working
// set). bf16 halves the replicated bytes. f32 register accumulation; final
// fused pass: out = embeds(f32) + L1+L2+L3 (bf16->f32).

static constexpr int USERS  = 50000;
static constexpr int NNODES = 100000;
static constexpr int DIM    = 128;
static constexpr int NEDGES = 1600000;
static constexpr long NELEM = (long)NNODES * DIM;   // 12.8M
static constexpr int SCAN_BLK = 256;
static constexpr int NBLKS = (NNODES + SCAN_BLK - 1) / SCAN_BLK;  // 391

__device__ __forceinline__ unsigned short f2bf(float f) {
    // RNE f32 -> bf16
    unsigned int u = __float_as_uint(f);
    unsigned int r = (u + 0x7FFFu + ((u >> 16) & 1)) >> 16;
    return (unsigned short)r;
}
__device__ __forceinline__ unsigned int pack2(float a, float b) {
    return (unsigned int)f2bf(a) | ((unsigned int)f2bf(b) << 16);
}
__device__ __forceinline__ float bflo(unsigned int p) { return __uint_as_float(p << 16); }
__device__ __forceinline__ float bfhi(unsigned int p) { return __uint_as_float(p & 0xFFFF0000u); }

// concat u/i embeds -> E0 (bf16). 8 elems/thread.
__global__ void init_k(const float* __restrict__ uE, const float* __restrict__ iE,
                       unsigned int* __restrict__ E0) {   // E0 as uint (2 bf16 each)
    long base = ((long)blockIdx.x * blockDim.x + threadIdx.x) * 8;
    if (base >= NELEM) return;
    const long usplit = (long)USERS * DIM;
    const float* s = (base < usplit) ? (uE + base) : (iE + (base - usplit));
    float4 f0 = *(const float4*)(s);
    float4 f1 = *(const float4*)(s + 4);
    uint4 o;
    o.x = pack2(f0.x, f0.y); o.y = pack2(f0.z, f0.w);
    o.z = pack2(f1.x, f1.y); o.w = pack2(f1.z, f1.w);
    *(uint4*)(E0 + base / 2) = o;
}

// ---------- CSR build ----------
__global__ void hist_k(const int* __restrict__ edst, int* __restrict__ counts) {
    int e = blockIdx.x * blockDim.x + threadIdx.x;
    if (e >= NEDGES) return;
    atomicAdd(&counts[edst[e]], 1);
}

__global__ void scan1_k(const int* __restrict__ counts, int* __restrict__ rs,
                        int* __restrict__ blk) {
    __shared__ int s[SCAN_BLK];
    int t = threadIdx.x;
    int i = blockIdx.x * SCAN_BLK + t;
    int v = (i < NNODES) ? counts[i] : 0;
    s[t] = v;
    __syncthreads();
    for (int off = 1; off < SCAN_BLK; off <<= 1) {
        int x = (t >= off) ? s[t - off] : 0;
        __syncthreads();
        s[t] += x;
        __syncthreads();
    }
    if (i < NNODES) rs[i] = s[t] - v;
    if (t == SCAN_BLK - 1) blk[blockIdx.x] = s[t];
}

__global__ void scan2_k(int* __restrict__ blk) {
    __shared__ int s[512];
    int t = threadIdx.x;
    int v = (t < NBLKS) ? blk[t] : 0;
    s[t] = v;
    __syncthreads();
    for (int off = 1; off < 512; off <<= 1) {
        int x = (t >= off) ? s[t - off] : 0;
        __syncthreads();
        s[t] += x;
        __syncthreads();
    }
    if (t < NBLKS) blk[t] = s[t] - v;
}

__global__ void scan3_k(int* __restrict__ rs, const int* __restrict__ blk,
                        int* __restrict__ cursor) {
    int i = blockIdx.x * SCAN_BLK + threadIdx.x;
    if (i == 0) rs[NNODES] = NEDGES;
    if (i >= NNODES) return;
    int v = rs[i] + blk[blockIdx.x];
    rs[i] = v;
    cursor[i] = v;
}

__global__ void fill_k(const int* __restrict__ esrc, const int* __restrict__ edst,
                       const float* __restrict__ eval,
                       int* __restrict__ cursor, int2* __restrict__ meta) {
    int e = blockIdx.x * blockDim.x + threadIdx.x;
    if (e >= NEDGES) return;
    int d = edst[e];
    int p = atomicAdd(&cursor[d], 1);
    meta[p] = make_int2(esrc[e], __float_as_int(eval[e]));
}

// ---------- gather: 1 wave/dest row; bf16 in, bf16 out; f32 accum ----------
__global__ void gather_k(const int* __restrict__ rs, const int2* __restrict__ meta,
                         const unsigned int* __restrict__ cur,  // [NNODES][64] uints
                         unsigned int* __restrict__ nxt) {
    int row = blockIdx.x * (blockDim.x >> 6) + (threadIdx.x >> 6);
    if (row >= NNODES) return;
    int lane = threadIdx.x & 63;
    int beg = rs[row], end = rs[row + 1];
    float sx = 0.f, sy = 0.f, tx = 0.f, ty = 0.f;
    int i = beg;
    for (; i + 1 < end; i += 2) {                 // 2 independent gather chains
        int2 m0 = meta[i];
        int2 m1 = meta[i + 1];
        unsigned int p0 = cur[(long)m0.x * 64 + lane];
        unsigned int p1 = cur[(long)m1.x * 64 + lane];
        float v0 = __int_as_float(m0.y);
        float v1 = __int_as_float(m1.y);
        sx += bflo(p0) * v0;  sy += bfhi(p0) * v0;
        tx += bflo(p1) * v1;  ty += bfhi(p1) * v1;
    }
    if (i < end) {
        int2 m = meta[i];
        unsigned int p = cur[(long)m.x * 64 + lane];
        float v = __int_as_float(m.y);
        sx += bflo(p) * v;  sy += bfhi(p) * v;
    }
    nxt[(long)row * 64 + lane] = pack2(sx + tx, sy + ty);
}

// ---------- final: out = embeds(f32) + L1 + L2 + L3 ----------
__global__ void final_k(const float* __restrict__ uE, const float* __restrict__ iE,
                        const unsigned int* __restrict__ L1,
                        const unsigned int* __restrict__ L2,
                        const unsigned int* __restrict__ L3,
                        float* __restrict__ out) {
    long base = ((long)blockIdx.x * blockDim.x + threadIdx.x) * 8;
    if (base >= NELEM) return;
    const long usplit = (long)USERS * DIM;
    const float* s = (base < usplit) ? (uE + base) : (iE + (base - usplit));
    float4 a = *(const float4*)(s);
    float4 b = *(const float4*)(s + 4);
    uint4 l1 = *(const uint4*)(L1 + base / 2);
    uint4 l2 = *(const uint4*)(L2 + base / 2);
    uint4 l3 = *(const uint4*)(L3 + base / 2);
    a.x += bflo(l1.x) + bflo(l2.x) + bflo(l3.x);
    a.y += bfhi(l1.x) + bfhi(l2.x) + bfhi(l3.x);
    a.z += bflo(l1.y) + bflo(l2.y) + bflo(l3.y);
    a.w += bfhi(l1.y) + bfhi(l2.y) + bfhi(l3.y);
    b.x += bflo(l1.z) + bflo(l2.z) + bflo(l3.z);
    b.y += bfhi(l1.z) + bfhi(l2.z) + bfhi(l3.z);
    b.z += bflo(l1.w) + bflo(l2.w) + bflo(l3.w);
    b.w += bfhi(l1.w) + bfhi(l2.w) + bfhi(l3.w);
    *(float4*)(out + base)     = a;
    *(float4*)(out + base + 4) = b;
}

// ---------- fallback: R2 atomic path (f32, needs 102.4MB) ----------
__global__ void init_f32_k(const float* __restrict__ uE, const float* __restrict__ iE,
                           float* __restrict__ acc, float* __restrict__ cur) {
    long base = ((long)blockIdx.x * blockDim.x + threadIdx.x) * 8;
    if (base >= NELEM) return;
    const long usplit = (long)USERS * DIM;
    const float* s = (base < usplit) ? (uE + base) : (iE + (base - usplit));
    float4 f0 = *(const float4*)(s);
    float4 f1 = *(const float4*)(s + 4);
    *(float4*)(acc + base)     = f0;
    *(float4*)(acc + base + 4) = f1;
    *(float4*)(cur + base)     = f0;
    *(float4*)(cur + base + 4) = f1;
}
__global__ void scatter_k(const int* __restrict__ esrc, const int* __restrict__ edst,
                          const float* __restrict__ eval,
                          const float* __restrict__ cur, float* __restrict__ nxt) {
    long g = (long)blockIdx.x * blockDim.x + threadIdx.x;
    if (g >= (long)NEDGES * 32) return;
    int e  = (int)(g >> 5);
    int d0 = ((int)g & 31) * 4;
    float v = eval[e];
    float4 x = *(const float4*)(cur + (long)esrc[e] * DIM + d0);
    float* o = nxt + (long)edst[e] * DIM + d0;
    unsafeAtomicAdd(o + 0, x.x * v);
    unsafeAtomicAdd(o + 1, x.y * v);
    unsafeAtomicAdd(o + 2, x.z * v);
    unsafeAtomicAdd(o + 3, x.w * v);
}
__global__ void add_k(float* __restrict__ acc, const float* __restrict__ nxt) {
    long g = ((long)blockIdx.x * blockDim.x + threadIdx.x) * 4;
    if (g >= NELEM) return;
    float4 a = *(const float4*)(acc + g);
    float4 n = *(const float4*)(nxt + g);
    a.x += n.x; a.y += n.y; a.z += n.z; a.w += n.w;
    *(float4*)(acc + g) = a;
}

extern "C" void kernel_launch(void* const* d_in, const int* in_sizes, int n_in,
                              void* d_out, int out_size, void* d_ws, size_t ws_size,
                              hipStream_t stream) {
    const float* uE   = (const float*)d_in[0];
    const float* iE   = (const float*)d_in[1];
    const int*   esrc = (const int*)d_in[2];
    const int*   edst = (const int*)d_in[3];
    const float* eval = (const float*)d_in[4];
    float* out = (float*)d_out;

    char* ws = (char*)d_ws;
    const long NU = NELEM / 2;                      // uints per layer buffer
    unsigned int* E0 = (unsigned int*)ws;           // 25.6 MB
    unsigned int* L1 = E0 + NU;                     // 25.6 MB
    unsigned int* L2 = L1 + NU;                     // 25.6 MB
    unsigned int* L3 = L2 + NU;                     // 25.6 MB
    int2* meta   = (int2*)(L3 + NU);                // 12.8 MB
    int*  rs     = (int*)(meta + NEDGES);           // NNODES+1
    int*  cursor = rs + NNODES + 1;                 // NNODES
    int*  blk    = cursor + NNODES;                 // 512
    size_t need  = (size_t)((char*)(blk + 512) - ws);

    if (ws_size >= need) {
        init_k<<<(int)((NELEM / 8 + 255) / 256), 256, 0, stream>>>(uE, iE, E0);

        hipMemsetAsync(cursor, 0, (size_t)NNODES * sizeof(int), stream);
        hist_k<<<(NEDGES + 255) / 256, 256, 0, stream>>>(edst, cursor);
        scan1_k<<<NBLKS, SCAN_BLK, 0, stream>>>(cursor, rs, blk);
        scan2_k<<<1, 512, 0, stream>>>(blk);
        scan3_k<<<NBLKS, SCAN_BLK, 0, stream>>>(rs, blk, cursor);
        fill_k<<<(NEDGES + 255) / 256, 256, 0, stream>>>(esrc, edst, eval, cursor, meta);

        const int gblocks = (NNODES * 64 + 255) / 256;
        gather_k<<<gblocks, 256, 0, stream>>>(rs, meta, E0, L1);
        gather_k<<<gblocks, 256, 0, stream>>>(rs, meta, L1, L2);
        gather_k<<<gblocks, 256, 0, stream>>>(rs, meta, L2, L3);

        final_k<<<(int)((NELEM / 8 + 255) / 256), 256, 0, stream>>>(uE, iE, L1, L2, L3, out);
    } else {
        // fallback: R2 atomic scatter (102.4 MB ws)
        float* bufA = (float*)ws;
        float* bufB = bufA + NELEM;
        const size_t SZ = (size_t)NELEM * sizeof(float);
        init_f32_k<<<(int)((NELEM / 8 + 255) / 256), 256, 0, stream>>>(uE, iE, out, bufA);
        float* cur = bufA;
        float* nxt = bufB;
        for (int l = 0; l < 3; ++l) {
            hipMemsetAsync(nxt, 0, SZ, stream);
            long nthreads = (long)NEDGES * 32;
            scatter_k<<<(int)((nthreads + 255) / 256), 256, 0, stream>>>(esrc, edst, eval, cur, nxt);
            add_k<<<(int)((NELEM / 4 + 255) / 256), 256, 0, stream>>>(out, nxt);
            float* t = cur; cur = nxt; nxt = t;
        }
    }
}